// Round 2
// baseline (156.171 us; speedup 1.0000x reference)
//
#include <hip/hip_runtime.h>
#include <hip/hip_bf16.h>
#include <cstdint>

#define BB 512
#define NN 512
#define FF 512
#define DD 256
#define KTOP 10
#define BN (BB*NN)         // 262144 rows
#define BM 32              // rows per tile
#define NTILES (BN/BM)     // 8192
#define GRID 512
#define TPB (NTILES/GRID)  // 16 tiles per block (chunked, contiguous memory per block)
#define LDAP 264           // padded LDS row length in ushorts

typedef __attribute__((ext_vector_type(8))) short bf16x8;
typedef __attribute__((ext_vector_type(4))) short s16x4;
typedef __attribute__((ext_vector_type(4))) float f32x4;

__device__ __forceinline__ ushort f2bf(float x){
  union { __hip_bfloat16 h; ushort u; } cv;
  cv.h = __float2bfloat16(x);   // hardware v_cvt (RNE); compiler fuses pairs to v_cvt_pk_bf16_f32
  return cv.u;
}

// ---------------- kernel 0: W f32 -> bf16 ----------------
__global__ void wconv(const float* __restrict__ W, ushort* __restrict__ Wbf){
  int i = (blockIdx.x*256 + threadIdx.x)*4;   // 64 blocks
  float4 v = *reinterpret_cast<const float4*>(W + i);
  s16x4 o;
  o[0] = (short)f2bf(v.x); o[1] = (short)f2bf(v.y);
  o[2] = (short)f2bf(v.z); o[3] = (short)f2bf(v.w);
  *reinterpret_cast<s16x4*>(Wbf + i) = o;
}

// ---------------- kernel 1: fused GEMM + bilinear reduce ----------------
// score[m] = attn[m] * sum_e dis[m,e] * sum_d W[e,d] * drug[m,d]
__global__ __launch_bounds__(256, 2)
void score_kernel(const float* __restrict__ emb, const float* __restrict__ attn,
                  const ushort* __restrict__ Wbf, float* __restrict__ scores){
  __shared__ ushort Abuf[2][BM*LDAP];   // drug tile, bf16, double-buffered
  __shared__ float red[4][BM];

  const int tid  = threadIdx.x;
  const int w    = tid >> 6;        // wave 0..3, owns e-range [w*64, w*64+64)
  const int lane = tid & 63;
  const int g    = lane >> 4;       // k-group / row-group
  const int c    = lane & 15;       // col-in-16

  // W B-fragments in registers: B[k][e] = W[e][k]. Lane: e = w*64+eb*16+c, k = kb*32+g*8..+8
  bf16x8 Wf[4][8];
#pragma unroll
  for (int eb = 0; eb < 4; ++eb)
#pragma unroll
    for (int kb = 0; kb < 8; ++kb){
      int e = w*64 + eb*16 + c;
      int k = kb*32 + g*8;
      Wf[eb][kb] = *reinterpret_cast<const bf16x8*>(Wbf + e*DD + k);
    }

  const int ch   = tid & 31;        // 8-float chunk within the 256-float drug half
  const int rsub = tid >> 5;        // 0..7
  const int tile0 = blockIdx.x * TPB;

  float4 pf[8];                     // prefetch regs: 32 floats/thread (drug half of next tile)

#define PF_LOAD(TILE) do {                                                   \
    const float* base_ = emb + (size_t)(TILE)*BM*FF;                         \
    _Pragma("unroll")                                                        \
    for (int it = 0; it < 4; ++it){                                          \
      const float* src_ = base_ + (it*8 + rsub)*FF + ch*8;                   \
      pf[it*2]   = *reinterpret_cast<const float4*>(src_);                   \
      pf[it*2+1] = *reinterpret_cast<const float4*>(src_ + 4);               \
    }                                                                        \
  } while(0)

#define LDS_WRITE(BUFI) do {                                                 \
    _Pragma("unroll")                                                        \
    for (int it = 0; it < 4; ++it){                                          \
      float4 a_ = pf[it*2], b_ = pf[it*2+1];                                 \
      bf16x8 p_;                                                             \
      p_[0]=(short)f2bf(a_.x); p_[1]=(short)f2bf(a_.y);                      \
      p_[2]=(short)f2bf(a_.z); p_[3]=(short)f2bf(a_.w);                      \
      p_[4]=(short)f2bf(b_.x); p_[5]=(short)f2bf(b_.y);                      \
      p_[6]=(short)f2bf(b_.z); p_[7]=(short)f2bf(b_.w);                      \
      *reinterpret_cast<bf16x8*>(&Abuf[BUFI][(it*8 + rsub)*LDAP + ch*8]) = p_;\
    }                                                                        \
  } while(0)

  PF_LOAD(tile0);
  LDS_WRITE(0);
  __syncthreads();

  int cur = 0;
  for (int t = 0; t < TPB; ++t){
    const int tile = tile0 + t;
    if (t + 1 < TPB) PF_LOAD(tile + 1);     // async: results consumed only after compute

    const float* disp = emb + (size_t)tile*BM*FF + DD;  // dis half, f32 direct from global

#pragma unroll
    for (int mb = 0; mb < 2; ++mb){
      const int m0 = mb*16;
      bf16x8 af[8];
#pragma unroll
      for (int kb = 0; kb < 8; ++kb)
        af[kb] = *reinterpret_cast<const bf16x8*>(&Abuf[cur][(m0 + c)*LDAP + kb*32 + g*8]);

      float dv[16];                          // dv[j*4+eb], compile-time indexed
#pragma unroll
      for (int j = 0; j < 4; ++j)
#pragma unroll
        for (int eb = 0; eb < 4; ++eb)
          dv[j*4+eb] = disp[(m0 + g*4 + j)*FF + w*64 + eb*16 + c];

      float rs0=0.f, rs1=0.f, rs2=0.f, rs3=0.f;
#pragma unroll
      for (int eb = 0; eb < 4; ++eb){
        f32x4 acc = {0.f, 0.f, 0.f, 0.f};
#pragma unroll
        for (int kb = 0; kb < 8; ++kb)
          acc = __builtin_amdgcn_mfma_f32_16x16x32_bf16(af[kb], Wf[eb][kb], acc, 0, 0, 0);
        rs0 += acc[0] * dv[0*4+eb];
        rs1 += acc[1] * dv[1*4+eb];
        rs2 += acc[2] * dv[2*4+eb];
        rs3 += acc[3] * dv[3*4+eb];
      }
      // reduce across the 16 c-lanes (same rows, different e columns)
      rs0 += __shfl_xor(rs0,1); rs0 += __shfl_xor(rs0,2); rs0 += __shfl_xor(rs0,4); rs0 += __shfl_xor(rs0,8);
      rs1 += __shfl_xor(rs1,1); rs1 += __shfl_xor(rs1,2); rs1 += __shfl_xor(rs1,4); rs1 += __shfl_xor(rs1,8);
      rs2 += __shfl_xor(rs2,1); rs2 += __shfl_xor(rs2,2); rs2 += __shfl_xor(rs2,4); rs2 += __shfl_xor(rs2,8);
      rs3 += __shfl_xor(rs3,1); rs3 += __shfl_xor(rs3,2); rs3 += __shfl_xor(rs3,4); rs3 += __shfl_xor(rs3,8);
      if (c == 0){
        red[w][m0 + g*4 + 0] = rs0;
        red[w][m0 + g*4 + 1] = rs1;
        red[w][m0 + g*4 + 2] = rs2;
        red[w][m0 + g*4 + 3] = rs3;
      }
    }
    __syncthreads();                         // red ready; all reads of Abuf[cur] done
    if (tid < BM){
      int row = tile*BM + tid;
      scores[row] = attn[row] * (red[0][tid] + red[1][tid] + red[2][tid] + red[3][tid]);
    }
    if (t + 1 < TPB) LDS_WRITE(cur ^ 1);     // drain prefetch into the other buffer
    __syncthreads();                         // next tile's buffer ready; red protected
    cur ^= 1;
  }
#undef PF_LOAD
#undef LDS_WRITE
}

// ---------------- kernel 2: per-batch top-K mean ----------------
__global__ void topk_kernel(const float* __restrict__ scores, float* __restrict__ out){
  const int b = blockIdx.x;
  const int lane = threadIdx.x;   // 64 threads
  float v0,v1,v2,v3,v4,v5,v6,v7;
  const float* s = scores + b*NN;
  v0=s[lane]; v1=s[64+lane]; v2=s[128+lane]; v3=s[192+lane];
  v4=s[256+lane]; v5=s[320+lane]; v6=s[384+lane]; v7=s[448+lane];
  float total = 0.f;
  for (int it = 0; it < KTOP; ++it){
    float m = v0; int mj = 0;
    if (v1>m){m=v1;mj=1;} if (v2>m){m=v2;mj=2;} if (v3>m){m=v3;mj=3;}
    if (v4>m){m=v4;mj=4;} if (v5>m){m=v5;mj=5;} if (v6>m){m=v6;mj=6;}
    if (v7>m){m=v7;mj=7;}
    float bm = m; int bl = lane;
#pragma unroll
    for (int off = 32; off; off >>= 1){
      float om = __shfl_xor(bm, off);
      int   ol = __shfl_xor(bl, off);
      if (om > bm || (om == bm && ol < bl)){ bm = om; bl = ol; }
    }
    total += bm;
    if (lane == bl){
      if (mj==0) v0=-3.0e38f; else if (mj==1) v1=-3.0e38f;
      else if (mj==2) v2=-3.0e38f; else if (mj==3) v3=-3.0e38f;
      else if (mj==4) v4=-3.0e38f; else if (mj==5) v5=-3.0e38f;
      else if (mj==6) v6=-3.0e38f; else v7=-3.0e38f;
    }
  }
  if (lane == 0) out[b] = total * (1.0f / KTOP);
}

extern "C" void kernel_launch(void* const* d_in, const int* in_sizes, int n_in,
                              void* d_out, int out_size, void* d_ws, size_t ws_size,
                              hipStream_t stream){
  const float* emb  = (const float*)d_in[0];   // (B,N,F) f32
  const float* attn = (const float*)d_in[1];   // (B,N,1) f32
  const float* W    = (const float*)d_in[2];   // (D,D) f32
  float* out = (float*)d_out;                  // (B,1) f32

  ushort* Wbf    = (ushort*)d_ws;                                 // 128 KB
  float*  scores = (float*)((char*)d_ws + DD*DD*sizeof(ushort));  // 1 MB

  wconv<<<64, 256, 0, stream>>>(W, Wbf);
  score_kernel<<<GRID, 256, 0, stream>>>(emb, attn, Wbf, scores);
  topk_kernel<<<BB, 64, 0, stream>>>(scores, out);
}

// Round 3
// 130.156 us; speedup vs baseline: 1.1999x; 1.1999x over previous
//
#include <hip/hip_runtime.h>
#include <hip/hip_bf16.h>
#include <cstdint>

#define BB 512
#define NN 512
#define FF 512
#define DD 256
#define KTOP 10
#define BN (BB*NN)         // 262144 rows
#define BM 64              // rows per tile
#define NTILES (BN/BM)     // 4096
#define GRID 256           // 1 block per CU
#define TPB (NTILES/GRID)  // 16 tiles per block
#define LDAP 264           // padded LDS row stride in ushorts (528B = 33*16B, b128-aligned)

typedef __attribute__((ext_vector_type(8))) short bf16x8;
typedef __attribute__((ext_vector_type(4))) short s16x4;
typedef __attribute__((ext_vector_type(4))) float f32x4;

__device__ __forceinline__ ushort f2bf(float x){
  union { __hip_bfloat16 h; ushort u; } cv;
  cv.h = __float2bfloat16(x);   // hardware RNE cvt; pairs fuse to v_cvt_pk_bf16_f32
  return cv.u;
}
__device__ __forceinline__ float bf2f(ushort b){
  return __uint_as_float(((uint32_t)b) << 16);
}

// ---------------- kernel 0: W f32 -> bf16 ----------------
__global__ void wconv(const float* __restrict__ W, ushort* __restrict__ Wbf){
  int i = (blockIdx.x*256 + threadIdx.x)*4;   // 64 blocks
  float4 v = *reinterpret_cast<const float4*>(W + i);
  s16x4 o;
  o[0] = (short)f2bf(v.x); o[1] = (short)f2bf(v.y);
  o[2] = (short)f2bf(v.z); o[3] = (short)f2bf(v.w);
  *reinterpret_cast<s16x4*>(Wbf + i) = o;
}

// ---------------- kernel 1: fused GEMM + bilinear reduce ----------------
// score[m] = attn[m] * sum_e dis[m,e] * sum_k W[e,k] * drug[m,k]
// 8 waves: wave w -> e-slice s=w&3 (64 cols), k-half h=w>>2 (128 of 256).
// Bilinear is linear in (e,k) pieces, so per-wave partial sums add in red[][].
__global__ __launch_bounds__(512, 2)
void score_kernel(const float* __restrict__ emb, const float* __restrict__ attn,
                  const ushort* __restrict__ Wbf, float* __restrict__ scores){
  __shared__ ushort Abuf[2][BM*LDAP];   // drug tile bf16, double-buffered (67.5 KB)
  __shared__ ushort Sbuf[2][BM*LDAP];   // dis  tile bf16, double-buffered (67.5 KB)
  __shared__ float red[8][BM];          // 2 KB

  const int tid  = threadIdx.x;
  const int w    = tid >> 6;        // wave 0..7
  const int lane = tid & 63;
  const int g    = lane >> 4;       // row-group / k-subgroup
  const int c    = lane & 15;       // col-in-16
  const int s    = w & 3;           // e-slice
  const int h    = w >> 2;          // k-half

  // W B-fragments: B[k][e] = W[e][k]. Lane: e = s*64+eb*16+c, k = h*128+kb*32+g*8..+8
  bf16x8 Wf[4][4];                  // 64 VGPRs
#pragma unroll
  for (int eb = 0; eb < 4; ++eb)
#pragma unroll
    for (int kb = 0; kb < 4; ++kb){
      int e = s*64 + eb*16 + c;
      int k = h*128 + kb*32 + g*8;
      Wf[eb][kb] = *reinterpret_cast<const bf16x8*>(Wbf + e*DD + k);
    }

  const int ch   = tid & 63;        // 8-float chunk within a 512-float row
  const int rsub = tid >> 6;        // 0..7; thread stages rows rsub, rsub+8, ...
  const int tile0 = blockIdx.x * TPB;

  float4 pf[16];                    // 64 VGPRs: full next-tile stage (64 floats/thread)

#define PF_LOAD(TILE) do {                                                    \
    const float* base_ = emb + (size_t)(TILE)*BM*FF;                          \
    _Pragma("unroll")                                                         \
    for (int it = 0; it < 8; ++it){                                           \
      const float* src_ = base_ + (it*8 + rsub)*FF + ch*8;                    \
      pf[it*2]   = *reinterpret_cast<const float4*>(src_);                    \
      pf[it*2+1] = *reinterpret_cast<const float4*>(src_ + 4);                \
    }                                                                         \
  } while(0)

#define LDS_WRITE(BUFI) do {                                                  \
    _Pragma("unroll")                                                         \
    for (int it = 0; it < 8; ++it){                                           \
      int row_ = it*8 + rsub;                                                 \
      float4 a_ = pf[it*2], b_ = pf[it*2+1];                                  \
      bf16x8 p_;                                                              \
      p_[0]=(short)f2bf(a_.x); p_[1]=(short)f2bf(a_.y);                       \
      p_[2]=(short)f2bf(a_.z); p_[3]=(short)f2bf(a_.w);                       \
      p_[4]=(short)f2bf(b_.x); p_[5]=(short)f2bf(b_.y);                       \
      p_[6]=(short)f2bf(b_.z); p_[7]=(short)f2bf(b_.w);                       \
      ushort* dst_ = (ch < 32) ? &Abuf[BUFI][row_*LDAP + ch*8]                \
                               : &Sbuf[BUFI][row_*LDAP + (ch-32)*8];          \
      *reinterpret_cast<bf16x8*>(dst_) = p_;                                  \
    }                                                                         \
  } while(0)

  PF_LOAD(tile0);
  LDS_WRITE(0);
  __syncthreads();

  int cur = 0;
  for (int t = 0; t < TPB; ++t){
    const int tile = tile0 + t;
    if (t + 1 < TPB) PF_LOAD(tile + 1);   // in flight through compute + barrier drain

#pragma unroll
    for (int mb = 0; mb < 4; ++mb){
      const int m0 = mb*16;
      bf16x8 af[4];
#pragma unroll
      for (int kb = 0; kb < 4; ++kb)
        af[kb] = *reinterpret_cast<const bf16x8*>(
                     &Abuf[cur][(m0 + c)*LDAP + h*128 + kb*32 + g*8]);

      float rs0=0.f, rs1=0.f, rs2=0.f, rs3=0.f;
#pragma unroll
      for (int eb = 0; eb < 4; ++eb){
        f32x4 acc = {0.f, 0.f, 0.f, 0.f};
#pragma unroll
        for (int kb = 0; kb < 4; ++kb)
          acc = __builtin_amdgcn_mfma_f32_16x16x32_bf16(af[kb], Wf[eb][kb], acc, 0, 0, 0);
        // C[m0+g*4+j][s*64+eb*16+c] in acc[j]  (layout verified in R1: passed)
        const int e_loc = s*64 + eb*16 + c;
        rs0 += acc[0] * bf2f(Sbuf[cur][(m0 + g*4 + 0)*LDAP + e_loc]);
        rs1 += acc[1] * bf2f(Sbuf[cur][(m0 + g*4 + 1)*LDAP + e_loc]);
        rs2 += acc[2] * bf2f(Sbuf[cur][(m0 + g*4 + 2)*LDAP + e_loc]);
        rs3 += acc[3] * bf2f(Sbuf[cur][(m0 + g*4 + 3)*LDAP + e_loc]);
      }
      // reduce across the 16 c-lanes (e-columns within this wave's slice)
      rs0 += __shfl_xor(rs0,1); rs0 += __shfl_xor(rs0,2); rs0 += __shfl_xor(rs0,4); rs0 += __shfl_xor(rs0,8);
      rs1 += __shfl_xor(rs1,1); rs1 += __shfl_xor(rs1,2); rs1 += __shfl_xor(rs1,4); rs1 += __shfl_xor(rs1,8);
      rs2 += __shfl_xor(rs2,1); rs2 += __shfl_xor(rs2,2); rs2 += __shfl_xor(rs2,4); rs2 += __shfl_xor(rs2,8);
      rs3 += __shfl_xor(rs3,1); rs3 += __shfl_xor(rs3,2); rs3 += __shfl_xor(rs3,4); rs3 += __shfl_xor(rs3,8);
      if (c == 0){
        red[w][m0 + g*4 + 0] = rs0;
        red[w][m0 + g*4 + 1] = rs1;
        red[w][m0 + g*4 + 2] = rs2;
        red[w][m0 + g*4 + 3] = rs3;
      }
    }
    __syncthreads();                       // red ready; Abuf/Sbuf[cur] reads done; pf drained
    if (tid < BM){
      int row = tile*BM + tid;
      scores[row] = attn[row] * (red[0][tid] + red[1][tid] + red[2][tid] + red[3][tid]
                               + red[4][tid] + red[5][tid] + red[6][tid] + red[7][tid]);
    }
    if (t + 1 < TPB) LDS_WRITE(cur ^ 1);   // cvt + ds_write the prefetched tile
    __syncthreads();                       // next buffers ready; red protected
    cur ^= 1;
  }
#undef PF_LOAD
#undef LDS_WRITE
}

// ---------------- kernel 2: per-batch top-K mean ----------------
__global__ void topk_kernel(const float* __restrict__ scores, float* __restrict__ out){
  const int b = blockIdx.x;
  const int lane = threadIdx.x;   // 64 threads
  float v0,v1,v2,v3,v4,v5,v6,v7;
  const float* sc = scores + b*NN;
  v0=sc[lane]; v1=sc[64+lane]; v2=sc[128+lane]; v3=sc[192+lane];
  v4=sc[256+lane]; v5=sc[320+lane]; v6=sc[384+lane]; v7=sc[448+lane];
  float total = 0.f;
  for (int it = 0; it < KTOP; ++it){
    float m = v0; int mj = 0;
    if (v1>m){m=v1;mj=1;} if (v2>m){m=v2;mj=2;} if (v3>m){m=v3;mj=3;}
    if (v4>m){m=v4;mj=4;} if (v5>m){m=v5;mj=5;} if (v6>m){m=v6;mj=6;}
    if (v7>m){m=v7;mj=7;}
    float bm = m; int bl = lane;
#pragma unroll
    for (int off = 32; off; off >>= 1){
      float om = __shfl_xor(bm, off);
      int   ol = __shfl_xor(bl, off);
      if (om > bm || (om == bm && ol < bl)){ bm = om; bl = ol; }
    }
    total += bm;
    if (lane == bl){
      if (mj==0) v0=-3.0e38f; else if (mj==1) v1=-3.0e38f;
      else if (mj==2) v2=-3.0e38f; else if (mj==3) v3=-3.0e38f;
      else if (mj==4) v4=-3.0e38f; else if (mj==5) v5=-3.0e38f;
      else if (mj==6) v6=-3.0e38f; else v7=-3.0e38f;
    }
  }
  if (lane == 0) out[b] = total * (1.0f / KTOP);
}

extern "C" void kernel_launch(void* const* d_in, const int* in_sizes, int n_in,
                              void* d_out, int out_size, void* d_ws, size_t ws_size,
                              hipStream_t stream){
  const float* emb  = (const float*)d_in[0];   // (B,N,F) f32
  const float* attn = (const float*)d_in[1];   // (B,N,1) f32
  const float* W    = (const float*)d_in[2];   // (D,D) f32
  float* out = (float*)d_out;                  // (B,1) f32

  ushort* Wbf    = (ushort*)d_ws;                                 // 128 KB
  float*  scores = (float*)((char*)d_ws + DD*DD*sizeof(ushort));  // 1 MB

  wconv<<<64, 256, 0, stream>>>(W, Wbf);
  score_kernel<<<GRID, 512, 0, stream>>>(emb, attn, Wbf, scores);
  topk_kernel<<<BB, 64, 0, stream>>>(scores, out);
}

// Round 4
// 109.955 us; speedup vs baseline: 1.4203x; 1.1837x over previous
//
#include <hip/hip_runtime.h>
#include <hip/hip_bf16.h>
#include <cstdint>

#define BB 512
#define NN 512
#define FF 512
#define DD 256
#define KTOP 10
#define BN (BB*NN)          // 262144 rows
#define BM 32               // rows per tile
#define NTILES (BN/BM)      // 8192
#define GRID 256            // 1 block per CU
#define TPB (NTILES/GRID)   // 32 tiles per block, contiguous

typedef __attribute__((ext_vector_type(8))) short bf16x8;
typedef __attribute__((ext_vector_type(4))) short s16x4;
typedef __attribute__((ext_vector_type(4))) float f32x4;

__device__ __forceinline__ ushort f2bf(float x){
  union { __hip_bfloat16 h; ushort u; } cv;
  cv.h = __float2bfloat16(x);        // HW RNE; pairs fuse to v_cvt_pk_bf16_f32
  return cv.u;
}

__device__ __forceinline__ bf16x8 cvt8(f32x4 a, f32x4 b){
  bf16x8 r;
  r[0]=(short)f2bf(a[0]); r[1]=(short)f2bf(a[1]); r[2]=(short)f2bf(a[2]); r[3]=(short)f2bf(a[3]);
  r[4]=(short)f2bf(b[0]); r[5]=(short)f2bf(b[1]); r[6]=(short)f2bf(b[2]); r[7]=(short)f2bf(b[3]);
  return r;
}

// global f32 -> LDS, 16B per lane, linear LDS dest (wave-uniform base + lane*16).
// int->ptr casts avoid addrspace-cast issues; generic LDS ptr low 32 bits = LDS offset.
#define GL2LDS(GSRC, LDST)                                                          \
  __builtin_amdgcn_global_load_lds(                                                 \
      (const __attribute__((address_space(1))) uint32_t*)(uintptr_t)(GSRC),         \
      (__attribute__((address_space(3))) uint32_t*)(uint32_t)(uintptr_t)(LDST),     \
      16, 0, 0)

// ---------------- kernel 0: W f32 -> bf16 ----------------
__global__ void wconv(const float* __restrict__ W, ushort* __restrict__ Wbf){
  int i = (blockIdx.x*256 + threadIdx.x)*4;   // 64 blocks
  float4 v = *reinterpret_cast<const float4*>(W + i);
  s16x4 o;
  o[0] = (short)f2bf(v.x); o[1] = (short)f2bf(v.y);
  o[2] = (short)f2bf(v.z); o[3] = (short)f2bf(v.w);
  *reinterpret_cast<s16x4*>(Wbf + i) = o;
}

// ---------------- kernel 1: fused GEMM + bilinear reduce ----------------
// score[m] = attn[m] * sum_e dis[m,e] * sum_k W[e,k] * drug[m,k]
// 8 waves: wave w -> e-slice s=w&3 (64 cols), k-half h=w>>2.
// LDS tile: full f32 rows [32][512], chunk-XOR-swizzled: f32 col x of row r lives at
// float index r*512 + ((x>>2) ^ (r&7))*4 + (x&3). Source pre-swizzled for gload_lds.
__global__ __launch_bounds__(512, 2)
void score_kernel(const float* __restrict__ emb, const float* __restrict__ attn,
                  const ushort* __restrict__ Wbf, float* __restrict__ scores){
  __shared__ float Lbuf[2][BM*FF];     // 2 x 64 KB
  __shared__ float red[2][8][BM];      // 2 KB
  __shared__ float attn_l[TPB*BM];     // 4 KB

  const int tid  = threadIdx.x;
  const int w    = tid >> 6;        // wave 0..7
  const int lane = tid & 63;
  const int g    = lane >> 4;
  const int c    = lane & 15;
  const int s    = w & 3;           // e-slice
  const int h    = w >> 2;          // k-half

  // attn for this block's 1024 rows -> LDS (covered by prologue barrier)
  attn_l[tid]       = attn[blockIdx.x*(TPB*BM) + tid];
  attn_l[tid + 512] = attn[blockIdx.x*(TPB*BM) + 512 + tid];

  // W B-fragments: B[k][e] = W[e][k]; e = s*64+eb*16+c, k = h*128+kb*32+g*8..+8  (64 VGPR)
  bf16x8 Wf[4][4];
#pragma unroll
  for (int eb = 0; eb < 4; ++eb)
#pragma unroll
    for (int kb = 0; kb < 4; ++kb){
      int e = s*64 + eb*16 + c;
      int k = h*128 + kb*32 + g*8;
      Wf[eb][kb] = *reinterpret_cast<const bf16x8*>(Wbf + e*DD + k);
    }

  // staging source offsets (f32 units): issue i covers LDS region (w*8+i)*1KB =
  // row r=(w*8+i)>>1, half hf=(w*8+i)&1; lane fetches global chunk (l ^ (r&7)) of that half.
  int offs[8];
#pragma unroll
  for (int i = 0; i < 8; ++i){
    int idx = w*8 + i;
    int r = idx >> 1, hf = idx & 1;
    offs[i] = r*FF + hf*256 + ((lane ^ (r & 7)) << 2);
  }
  const float* tbase = emb + (size_t)blockIdx.x * TPB * (BM*FF);

  // prologue: stage tile 0 -> buf 0
#pragma unroll
  for (int i = 0; i < 8; ++i)
    GL2LDS(tbase + offs[i], &Lbuf[0][(w*8 + i)*256]);
  __syncthreads();   // drains vmcnt(0): tile 0 resident

  int cur = 0;
  for (int t = 0; t < TPB; ++t){
    // issue next tile's loads first; they stream during compute, drain at the barrier
    if (t + 1 < TPB){
      const float* nb = tbase + (size_t)(t+1) * (BM*FF);
#pragma unroll
      for (int i = 0; i < 8; ++i)
        GL2LDS(nb + offs[i], &Lbuf[cur ^ 1][(w*8 + i)*256]);
    }

    const f32x4* Lv = (const f32x4*)&Lbuf[cur][0];
#pragma unroll
    for (int mb = 0; mb < 2; ++mb){
      const int m0 = mb*16;
      const int rb = (m0 + c)*128;        // row base in float4 units
      const int x  = c & 7;               // row&7 for row=m0+c
      bf16x8 af[4];
#pragma unroll
      for (int kb = 0; kb < 4; ++kb){     // drug chunks, swizzled lookup, cvt to bf16
        int ch0 = h*32 + kb*8 + g*2;
        f32x4 q0 = Lv[rb + ((ch0    ) ^ x)];
        f32x4 q1 = Lv[rb + ((ch0 + 1) ^ x)];
        af[kb] = cvt8(q0, q1);
      }
      float rs0=0.f, rs1=0.f, rs2=0.f, rs3=0.f;
#pragma unroll
      for (int eb = 0; eb < 4; ++eb){
        f32x4 acc = {0.f, 0.f, 0.f, 0.f};
#pragma unroll
        for (int kb = 0; kb < 4; ++kb)
          acc = __builtin_amdgcn_mfma_f32_16x16x32_bf16(af[kb], Wf[eb][kb], acc, 0, 0, 0);
        // C[m0+g*4+j][s*64+eb*16+c] in acc[j]; dis read from swizzled f32 LDS
        const int sb = 64 + s*16 + eb*4 + (c >> 2);   // dis chunk index (pre-XOR)
        const int e3 = c & 3;
#pragma unroll
        for (int j = 0; j < 4; ++j){
          const int row = m0 + g*4 + j;
          const int fi  = row*FF + ((sb ^ (row & 7)) << 2) + e3;
          float d = Lbuf[cur][fi];
          if      (j == 0) rs0 += acc[0]*d;
          else if (j == 1) rs1 += acc[1]*d;
          else if (j == 2) rs2 += acc[2]*d;
          else             rs3 += acc[3]*d;
        }
      }
      rs0 += __shfl_xor(rs0,1); rs0 += __shfl_xor(rs0,2); rs0 += __shfl_xor(rs0,4); rs0 += __shfl_xor(rs0,8);
      rs1 += __shfl_xor(rs1,1); rs1 += __shfl_xor(rs1,2); rs1 += __shfl_xor(rs1,4); rs1 += __shfl_xor(rs1,8);
      rs2 += __shfl_xor(rs2,1); rs2 += __shfl_xor(rs2,2); rs2 += __shfl_xor(rs2,4); rs2 += __shfl_xor(rs2,8);
      rs3 += __shfl_xor(rs3,1); rs3 += __shfl_xor(rs3,2); rs3 += __shfl_xor(rs3,4); rs3 += __shfl_xor(rs3,8);
      if (c == 0){
        red[cur][w][m0 + g*4 + 0] = rs0;
        red[cur][w][m0 + g*4 + 1] = rs1;
        red[cur][w][m0 + g*4 + 2] = rs2;
        red[cur][w][m0 + g*4 + 3] = rs3;
      }
    }

    __syncthreads();   // single barrier: drains next-tile loads, syncs red[cur]

    if (tid < BM){
      float sum = red[cur][0][tid] + red[cur][1][tid] + red[cur][2][tid] + red[cur][3][tid]
                + red[cur][4][tid] + red[cur][5][tid] + red[cur][6][tid] + red[cur][7][tid];
      int row = (blockIdx.x*TPB + t)*BM + tid;
      scores[row] = attn_l[t*BM + tid] * sum;
    }
    cur ^= 1;
  }
}

// ---------------- kernel 2: per-batch top-K mean ----------------
__global__ void topk_kernel(const float* __restrict__ scores, float* __restrict__ out){
  const int b = blockIdx.x;
  const int lane = threadIdx.x;   // 64 threads
  float v0,v1,v2,v3,v4,v5,v6,v7;
  const float* sc = scores + b*NN;
  v0=sc[lane]; v1=sc[64+lane]; v2=sc[128+lane]; v3=sc[192+lane];
  v4=sc[256+lane]; v5=sc[320+lane]; v6=sc[384+lane]; v7=sc[448+lane];
  float total = 0.f;
  for (int it = 0; it < KTOP; ++it){
    float m = v0; int mj = 0;
    if (v1>m){m=v1;mj=1;} if (v2>m){m=v2;mj=2;} if (v3>m){m=v3;mj=3;}
    if (v4>m){m=v4;mj=4;} if (v5>m){m=v5;mj=5;} if (v6>m){m=v6;mj=6;}
    if (v7>m){m=v7;mj=7;}
    float bm = m; int bl = lane;
#pragma unroll
    for (int off = 32; off; off >>= 1){
      float om = __shfl_xor(bm, off);
      int   ol = __shfl_xor(bl, off);
      if (om > bm || (om == bm && ol < bl)){ bm = om; bl = ol; }
    }
    total += bm;
    if (lane == bl){
      if (mj==0) v0=-3.0e38f; else if (mj==1) v1=-3.0e38f;
      else if (mj==2) v2=-3.0e38f; else if (mj==3) v3=-3.0e38f;
      else if (mj==4) v4=-3.0e38f; else if (mj==5) v5=-3.0e38f;
      else if (mj==6) v6=-3.0e38f; else v7=-3.0e38f;
    }
  }
  if (lane == 0) out[b] = total * (1.0f / KTOP);
}

extern "C" void kernel_launch(void* const* d_in, const int* in_sizes, int n_in,
                              void* d_out, int out_size, void* d_ws, size_t ws_size,
                              hipStream_t stream){
  const float* emb  = (const float*)d_in[0];   // (B,N,F) f32
  const float* attn = (const float*)d_in[1];   // (B,N,1) f32
  const float* W    = (const float*)d_in[2];   // (D,D) f32
  float* out = (float*)d_out;                  // (B,1) f32

  ushort* Wbf    = (ushort*)d_ws;                                 // 128 KB
  float*  scores = (float*)((char*)d_ws + DD*DD*sizeof(ushort));  // 1 MB

  wconv<<<64, 256, 0, stream>>>(W, Wbf);
  score_kernel<<<GRID, 512, 0, stream>>>(emb, attn, Wbf, scores);
  topk_kernel<<<BB, 64, 0, stream>>>(scores, out);
}